// Round 2
// baseline (6263.007 us; speedup 1.0000x reference)
//
#include <hip/hip_runtime.h>
#include <hip/hip_bf16.h>

// RK4 latent ODE: f(y) = tanh(y@W1+b1)@W2 + b2. B=1024, D=512, H=1024, T=64.
// R7 passed (absmax 0.031) at 4.03 ms: per-CU L2-fill saturated at 136 GB/s
// (94% of ceiling) streaming the FULL 2MB weights per block per stage.
// R8: 4-way K-split. 256 blocks = 64 row-groups x 4 weight-quarters; each
// block streams only 512KB/stage (W1 col-quarter + W2 K-quarter), computes a
// partial k over its h-quarter, exchanges partials via global + device-scope
// flags (double-buffered by stage parity, monotone counters, memset per
// launch). y-state replicated per block (bitwise-identical via canonical sum
// order); only q==0 writes output. Same proven numerics as R7.

#define B_ 1024
#define D_ 512
#define H_ 1024
#define T_ 64
#define M_ 16   // batch rows per row-group

typedef unsigned short ushort_t;
typedef _Float16 f16x8 __attribute__((ext_vector_type(8)));
typedef float f32x4 __attribute__((ext_vector_type(4)));
typedef unsigned short ushortx8 __attribute__((ext_vector_type(8)));

__device__ __forceinline__ float bf2f(ushort_t u) {
  union { unsigned u; float f; } v;
  v.u = ((unsigned)u) << 16;
  return v.f;
}

__device__ __forceinline__ ushort_t f2h(float f) {
  return __builtin_bit_cast(ushort_t, (_Float16)f);   // RNE fp16
}

__device__ __forceinline__ float ldf(const void* p, int i, bool f32) {
  return f32 ? ((const float*)p)[i] : bf2f(((const ushort_t*)p)[i]);
}

__device__ __forceinline__ bool is_f32_inputs(const void* ts) {
  return ((const ushort_t*)ts)[1] == 0;
}

__device__ __forceinline__ float tanh_fast(float x) {
  float e = __builtin_amdgcn_exp2f(x * 2.885390081777927f);  // exp(2x)
  return 1.0f - 2.0f * __builtin_amdgcn_rcpf(e + 1.0f);      // NaN-free
}

__device__ __forceinline__ f16x8 ld8(const ushort_t* p) {
  return __builtin_bit_cast(f16x8, *(const ushortx8*)p);
}

__device__ __forceinline__ f32x4 mfma16f(f16x8 a, f16x8 b, f32x4 c) {
  return __builtin_amdgcn_mfma_f32_16x16x32_f16(a, b, c, 0, 0, 0);
}

// ---- pack W1 [D][H] -> per-(q,wave) fragment stream, fp16 ----
// half idx = tid*8+j, tid = q*16384 + w*1024 + t*64 + l
//   value = fp16( W1[ t*32 + (l>>4)*8 + j ][ q*256 + w*16 + (l&15) ] )
__global__ void pack_w1(const void* __restrict__ in, ushort_t* __restrict__ out,
                        const void* __restrict__ ts) {
  const bool f32 = is_f32_inputs(ts);
  const int tid = blockIdx.x * blockDim.x + threadIdx.x;  // 0..65535
  const int l = tid & 63;
  const int t = (tid >> 6) & 15;
  const int w = (tid >> 10) & 15;
  const int q = (tid >> 14) & 3;
  const int col = q * 256 + w * 16 + (l & 15);   // H index
  const int kb  = t * 32 + (l >> 4) * 8;          // D (K) index base
  ushortx8 v;
#pragma unroll
  for (int j = 0; j < 8; j++)
    v[j] = f2h(ldf(in, (size_t)(kb + j) * H_ + col, f32));
  *(ushortx8*)(out + (size_t)tid * 8) = v;
}

// ---- pack W2 [H][D] -> per-(q,wave) fragment stream, fp16 ----
// half idx = tid*8+j, tid = q*16384 + w*1024 + t*128 + n*64 + l
//   value = fp16( W2[ q*256 + t*32 + (l>>4)*8 + j ][ w*32 + n*16 + (l&15) ] )
__global__ void pack_w2(const void* __restrict__ in, ushort_t* __restrict__ out,
                        const void* __restrict__ ts) {
  const bool f32 = is_f32_inputs(ts);
  const int tid = blockIdx.x * blockDim.x + threadIdx.x;  // 0..65535
  const int l = tid & 63;
  const int n = (tid >> 6) & 1;
  const int t = (tid >> 7) & 7;
  const int w = (tid >> 10) & 15;
  const int q = (tid >> 14) & 3;
  const int col = w * 32 + n * 16 + (l & 15);          // D index
  const int kb  = q * 256 + t * 32 + (l >> 4) * 8;     // H (K) index base
  ushortx8 v;
#pragma unroll
  for (int j = 0; j < 8; j++)
    v[j] = f2h(ldf(in, (size_t)(kb + j) * D_ + col, f32));
  *(ushortx8*)(out + (size_t)tid * 8) = v;
}

// ---- main kernel: 256 blocks x 1024 threads ----
// bid -> q = (bid>>3)&3, rg = (bid&7) + 8*(bid>>5): row-group partners share
// bid%8 (same XCD under round-robin; correctness via agent-scope fences).
// GEMM1: wave w -> h col-tile [q*256 + w*16, +16), K=512 (16 iters).
// GEMM2: wave w -> partial k cols [w*32,+32) (2 tiles), K=256 local (8 iters).
__global__ __launch_bounds__(1024, 4)
void rk4_kernel(const void* __restrict__ y0,     // [B][D]
                const void* __restrict__ ts,     // [T]
                const ushort_t* __restrict__ w1p,// packed W1 streams
                const void* __restrict__ b1,     // [H]
                const ushort_t* __restrict__ w2p,// packed W2 streams
                const void* __restrict__ b2,     // [D]
                float* __restrict__ part,        // [2][64][4][16][512] fp32
                unsigned int* __restrict__ flags,// [64][4] x 16-uint stride
                float* __restrict__ out)         // [T][B][D] fp32
{
  __shared__ __align__(16) ushort_t yS[M_][D_ + 8];   // fp16 yin (16x512)
  __shared__ __align__(16) ushort_t hS[M_][256 + 8];  // fp16 local h quarter

  const bool f32i = is_f32_inputs(ts);
  const int tid  = threadIdx.x;
  const int wave = tid >> 6;
  const int lane = tid & 63;
  const int m    = lane & 15;
  const int quad = lane >> 4;
  const int bid  = blockIdx.x;
  const int q    = (bid >> 3) & 3;
  const int rg   = (bid & 7) + ((bid >> 5) << 3);
  const int rowbase = rg * M_;
  const int cw2 = wave * 32;    // state/partial col base (D index)

  const float b1v = ldf(b1, q * 256 + wave * 16 + m, f32i);
  float b2v[2];
#pragma unroll
  for (int n = 0; n < 2; n++) b2v[n] = ldf(b2, cw2 + n * 16 + m, f32i);

  const ushort_t* q1 = w1p + ((size_t)(q * 16 + wave) << 13) + lane * 8;
  const ushort_t* q2 = w2p + ((size_t)(q * 16 + wave) << 13) + lane * 8;
  unsigned int* myflag = flags + ((rg * 4 + q) << 4);

  float y[2][4], acc[2][4], k[2][4];
#pragma unroll
  for (int n = 0; n < 2; n++)
#pragma unroll
    for (int r = 0; r < 4; r++) {
      const int row = rowbase + quad * 4 + r;
      const int col = cw2 + n * 16 + m;
      y[n][r] = ldf(y0, row * D_ + col, f32i);
      if (q == 0) out[(size_t)row * D_ + col] = y[n][r];   // t=0 plane
      k[n][r] = 0.0f;
      acc[n][r] = 0.0f;
    }

#pragma unroll 1
  for (int step = 0; step < T_ - 1; step++) {
    const float dt = ldf(ts, step + 1, f32i) - ldf(ts, step, f32i);

#pragma unroll 1
    for (int e = 0; e < 4; e++) {
      const float c = (e == 0) ? 0.0f : ((e == 3) ? dt : 0.5f * dt);
      const float wgt = ((e == 1) || (e == 2)) ? 2.0f : 1.0f;
      const int sidx = step * 4 + e;
      const int par  = sidx & 1;

      // ---- stage yin = y + c*k into LDS (fp16), all 512 cols ----
#pragma unroll
      for (int n = 0; n < 2; n++)
#pragma unroll
        for (int r = 0; r < 4; r++)
          yS[quad * 4 + r][cw2 + n * 16 + m] = f2h(y[n][r] + c * k[n][r]);
      __syncthreads();

      // ---- GEMM1: h quarter = yin @ W1[:, q-slice], 1 tile/wave, K=512 ----
      f32x4 hacc = (f32x4){0.f, 0.f, 0.f, 0.f};
      f16x8 a0 = ld8(&yS[m][quad * 8]);
      f16x8 b0 = ld8(q1);
#pragma unroll 4
      for (int t = 0; t < 16; t++) {
        const int tn = (t + 1) & 15;   // dummy wrap prefetch
        f16x8 a1 = ld8(&yS[m][tn * 32 + quad * 8]);
        f16x8 bn = ld8(q1 + tn * 512);
        hacc = mfma16f(a0, b0, hacc);
        a0 = a1; b0 = bn;
      }

      // ---- bias + tanh -> hS (fp16, local 256 cols) ----
#pragma unroll
      for (int r = 0; r < 4; r++)
        hS[quad * 4 + r][wave * 16 + m] = f2h(tanh_fast(hacc[r] + b1v));
      __syncthreads();

      // ---- GEMM2: partial k = h_q @ W2[q-slice, :], 2 tiles/wave, K=256 ----
      f32x4 kacc[2];
#pragma unroll
      for (int n = 0; n < 2; n++) kacc[n] = (f32x4){0.f, 0.f, 0.f, 0.f};
      f16x8 c0 = ld8(&hS[m][quad * 8]);
      f16x8 d0 = ld8(q2);
      f16x8 d1 = ld8(q2 + 512);
#pragma unroll 4
      for (int t = 0; t < 8; t++) {
        const int tn = (t + 1) & 7;    // dummy wrap prefetch
        f16x8 a1 = ld8(&hS[m][tn * 32 + quad * 8]);
        f16x8 e0 = ld8(q2 + tn * 1024);
        f16x8 e1 = ld8(q2 + tn * 1024 + 512);
        kacc[0] = mfma16f(c0, d0, kacc[0]);
        kacc[1] = mfma16f(c0, d1, kacc[1]);
        c0 = a1; d0 = e0; d1 = e1;
      }

      // ---- publish partial [16][512] fp32 ----
      {
        float* pb = part + ((size_t)((par * 64 + rg) * 4 + q) << 13);
#pragma unroll
        for (int n = 0; n < 2; n++)
#pragma unroll
          for (int r = 0; r < 4; r++)
            pb[(quad * 4 + r) * 512 + cw2 + n * 16 + m] = kacc[n][r];
      }
      __syncthreads();
      if (tid == 0) {
        __threadfence();               // release: partials visible device-wide
        atomicAdd(myflag, 1u);
      }
      // ---- gather partner flags (threads 0..3, skip own) ----
      if (tid < 4 && tid != q) {
        unsigned int* pf = flags + ((rg * 4 + tid) << 4);
        const unsigned int tgt = (unsigned int)(sidx + 1);
        int spins = 0;
        while (__hip_atomic_load(pf, __ATOMIC_RELAXED, __HIP_MEMORY_SCOPE_AGENT) < tgt) {
          __builtin_amdgcn_s_sleep(1);
          if (++spins > (1 << 19)) break;   // anti-wedge valve (never hit normally)
        }
        __threadfence();               // acquire: invalidate stale partials
      }
      __syncthreads();

      // ---- assemble k = sum_q partial + b2 (canonical order: replicas identical) ----
      {
        const float* pr = part + ((size_t)((par * 64 + rg) * 4) << 13);
#pragma unroll
        for (int n = 0; n < 2; n++)
#pragma unroll
          for (int r = 0; r < 4; r++) {
            const size_t eo = (size_t)(quad * 4 + r) * 512 + cw2 + n * 16 + m;
            float s = b2v[n];
#pragma unroll
            for (int qq = 0; qq < 4; qq++)
              s += (qq == q) ? kacc[n][r] : pr[((size_t)qq << 13) + eo];
            k[n][r] = s;
            if (e == 0) acc[n][r] = k[n][r];
            else        acc[n][r] += wgt * k[n][r];
          }
      }
    }

    // ---- y update + fp32 output store (q==0 only) ----
    float* op = out + (size_t)(step + 1) * B_ * D_;
    const float s = dt * (1.0f / 6.0f);
#pragma unroll
    for (int n = 0; n < 2; n++)
#pragma unroll
      for (int r = 0; r < 4; r++) {
        y[n][r] += s * acc[n][r];
        if (q == 0)
          op[(size_t)(rowbase + quad * 4 + r) * D_ + cw2 + n * 16 + m] = y[n][r];
      }
  }
}

extern "C" void kernel_launch(void* const* d_in, const int* in_sizes, int n_in,
                              void* d_out, int out_size, void* d_ws, size_t ws_size,
                              hipStream_t stream) {
  // ---- role mapping from in_sizes (proven R5): elements-or-bytes, dict-or-alpha ----
  int iTs = -1, sc = 1;
  for (int i = 0; i < n_in; i++)
    if (in_sizes[i] == 64 || in_sizes[i] == 128 || in_sizes[i] == 256) {
      iTs = i; sc = in_sizes[i] / 64; break;
    }
  if (iTs < 0) { iTs = 1; sc = 1; }
  int iB1 = -1, iB2 = -1, bigs[3]; int nb = 0;
  for (int i = 0; i < n_in; i++) {
    if (i == iTs) continue;
    if (in_sizes[i] == 1024 * sc) iB1 = i;
    else if (in_sizes[i] == 512 * sc) iB2 = i;
    else if (nb < 3) bigs[nb++] = i;
  }
  if (iB1 < 0) iB1 = 3;
  if (iB2 < 0) iB2 = 5;
  if (nb < 3) { bigs[0] = 0; bigs[1] = 2; bigs[2] = 4; }
  const void *y0, *w1, *w2;
  if (iTs == 1) {            // dict order: first_point, ts, W1, b1, W2, b2
    y0 = d_in[bigs[0]]; w1 = d_in[bigs[1]]; w2 = d_in[bigs[2]];
  } else {                   // alphabetical: W1, W2, b1, b2, first_point, ts
    w1 = d_in[bigs[0]]; w2 = d_in[bigs[1]]; y0 = d_in[bigs[2]];
  }
  const void* ts = d_in[iTs];
  const void* b1 = d_in[iB1];
  const void* b2 = d_in[iB2];
  float* out = (float*)d_out;

  // ws layout: w1p 1MB | w2p 1MB | flags 16KB | partials 16MB
  char* wsb = (char*)d_ws;
  ushort_t* w1p = (ushort_t*)wsb;
  ushort_t* w2p = (ushort_t*)(wsb + (1 << 20));
  unsigned int* flags = (unsigned int*)(wsb + (2 << 20));
  float* part = (float*)(wsb + (2 << 20) + 16384);

  hipMemsetAsync(flags, 0, 16384, stream);   // monotone counters start at 0

  pack_w1<<<dim3(256), dim3(256), 0, stream>>>(w1, w1p, ts);
  pack_w2<<<dim3(256), dim3(256), 0, stream>>>(w2, w2p, ts);

  rk4_kernel<<<dim3(256), dim3(1024), 0, stream>>>(y0, ts, w1p, b1, w2p, b2,
                                                   part, flags, out);
}

// Round 3
// 4151.850 us; speedup vs baseline: 1.5085x; 1.5085x over previous
//
#include <hip/hip_runtime.h>
#include <hip/hip_bf16.h>

// RK4 latent ODE: f(y) = tanh(y@W1+b1)@W2 + b2. B=1024, D=512, H=1024, T=64.
// R8 (4-way K-split + __threadfence exchange) regressed to 6.26 ms: the
// agent-scope ACQUIRE fence emits buffer_inv -> evicts the L2-resident packed
// weights every stage (FETCH 9MB->938MB), making the weight stream L2-cold and
// latency-bound. R9: same split/compute/flag protocol, but exchange via
// coherence-point accesses that never invalidate L2:
//   publish: cached stores + RELEASE atomicAdd (s_waitcnt + buffer_wbl2:
//            write-back WITHOUT invalidate -> weights stay L2-resident)
//   consume: relaxed AGENT atomic loads (sc0|sc1: bypass L1/L2, served by the
//            shared Infinity Cache) for flags and partials. No buffer_inv.
// All 4 quarters are summed from memory in canonical order (own quarter's
// round-trip returns identical bits) -> replicas stay bitwise identical.
// Numerics identical to R8 (passed, absmax 0.03125).

#define B_ 1024
#define D_ 512
#define H_ 1024
#define T_ 64
#define M_ 16   // batch rows per row-group

typedef unsigned short ushort_t;
typedef _Float16 f16x8 __attribute__((ext_vector_type(8)));
typedef float f32x4 __attribute__((ext_vector_type(4)));
typedef unsigned short ushortx8 __attribute__((ext_vector_type(8)));

__device__ __forceinline__ float bf2f(ushort_t u) {
  union { unsigned u; float f; } v;
  v.u = ((unsigned)u) << 16;
  return v.f;
}

__device__ __forceinline__ ushort_t f2h(float f) {
  return __builtin_bit_cast(ushort_t, (_Float16)f);   // RNE fp16
}

__device__ __forceinline__ float ldf(const void* p, int i, bool f32) {
  return f32 ? ((const float*)p)[i] : bf2f(((const ushort_t*)p)[i]);
}

__device__ __forceinline__ bool is_f32_inputs(const void* ts) {
  return ((const ushort_t*)ts)[1] == 0;
}

__device__ __forceinline__ float tanh_fast(float x) {
  float e = __builtin_amdgcn_exp2f(x * 2.885390081777927f);  // exp(2x)
  return 1.0f - 2.0f * __builtin_amdgcn_rcpf(e + 1.0f);      // NaN-free
}

__device__ __forceinline__ f16x8 ld8(const ushort_t* p) {
  return __builtin_bit_cast(f16x8, *(const ushortx8*)p);
}

__device__ __forceinline__ f32x4 mfma16f(f16x8 a, f16x8 b, f32x4 c) {
  return __builtin_amdgcn_mfma_f32_16x16x32_f16(a, b, c, 0, 0, 0);
}

// ---- pack W1 [D][H] -> per-(q,wave) fragment stream, fp16 ----
// half idx = tid*8+j, tid = q*16384 + w*1024 + t*64 + l
//   value = fp16( W1[ t*32 + (l>>4)*8 + j ][ q*256 + w*16 + (l&15) ] )
__global__ void pack_w1(const void* __restrict__ in, ushort_t* __restrict__ out,
                        const void* __restrict__ ts) {
  const bool f32 = is_f32_inputs(ts);
  const int tid = blockIdx.x * blockDim.x + threadIdx.x;  // 0..65535
  const int l = tid & 63;
  const int t = (tid >> 6) & 15;
  const int w = (tid >> 10) & 15;
  const int q = (tid >> 14) & 3;
  const int col = q * 256 + w * 16 + (l & 15);   // H index
  const int kb  = t * 32 + (l >> 4) * 8;          // D (K) index base
  ushortx8 v;
#pragma unroll
  for (int j = 0; j < 8; j++)
    v[j] = f2h(ldf(in, (size_t)(kb + j) * H_ + col, f32));
  *(ushortx8*)(out + (size_t)tid * 8) = v;
}

// ---- pack W2 [H][D] -> per-(q,wave) fragment stream, fp16 ----
// half idx = tid*8+j, tid = q*16384 + w*1024 + t*128 + n*64 + l
//   value = fp16( W2[ q*256 + t*32 + (l>>4)*8 + j ][ w*32 + n*16 + (l&15) ] )
__global__ void pack_w2(const void* __restrict__ in, ushort_t* __restrict__ out,
                        const void* __restrict__ ts) {
  const bool f32 = is_f32_inputs(ts);
  const int tid = blockIdx.x * blockDim.x + threadIdx.x;  // 0..65535
  const int l = tid & 63;
  const int n = (tid >> 6) & 1;
  const int t = (tid >> 7) & 7;
  const int w = (tid >> 10) & 15;
  const int q = (tid >> 14) & 3;
  const int col = w * 32 + n * 16 + (l & 15);          // D index
  const int kb  = q * 256 + t * 32 + (l >> 4) * 8;     // H (K) index base
  ushortx8 v;
#pragma unroll
  for (int j = 0; j < 8; j++)
    v[j] = f2h(ldf(in, (size_t)(kb + j) * D_ + col, f32));
  *(ushortx8*)(out + (size_t)tid * 8) = v;
}

// ---- main kernel: 256 blocks x 1024 threads ----
// bid -> q = (bid>>3)&3, rg = (bid&7) + 8*(bid>>5).
// GEMM1: wave w -> h col-tile [q*256 + w*16, +16), K=512 (16 iters).
// GEMM2: wave w -> partial k cols [w*32,+32) (2 tiles), K=256 local (8 iters).
__global__ __launch_bounds__(1024, 4)
void rk4_kernel(const void* __restrict__ y0,     // [B][D]
                const void* __restrict__ ts,     // [T]
                const ushort_t* __restrict__ w1p,// packed W1 streams
                const void* __restrict__ b1,     // [H]
                const ushort_t* __restrict__ w2p,// packed W2 streams
                const void* __restrict__ b2,     // [D]
                float* __restrict__ part,        // [2][64][4][16][512] fp32
                unsigned int* __restrict__ flags,// [64][4] x 16-uint stride
                float* __restrict__ out)         // [T][B][D] fp32
{
  __shared__ __align__(16) ushort_t yS[M_][D_ + 8];   // fp16 yin (16x512)
  __shared__ __align__(16) ushort_t hS[M_][256 + 8];  // fp16 local h quarter

  const bool f32i = is_f32_inputs(ts);
  const int tid  = threadIdx.x;
  const int wave = tid >> 6;
  const int lane = tid & 63;
  const int m    = lane & 15;
  const int quad = lane >> 4;
  const int bid  = blockIdx.x;
  const int q    = (bid >> 3) & 3;
  const int rg   = (bid & 7) + ((bid >> 5) << 3);
  const int rowbase = rg * M_;
  const int cw2 = wave * 32;    // state/partial col base (D index)

  const float b1v = ldf(b1, q * 256 + wave * 16 + m, f32i);
  float b2v[2];
#pragma unroll
  for (int n = 0; n < 2; n++) b2v[n] = ldf(b2, cw2 + n * 16 + m, f32i);

  const ushort_t* q1 = w1p + ((size_t)(q * 16 + wave) << 13) + lane * 8;
  const ushort_t* q2 = w2p + ((size_t)(q * 16 + wave) << 13) + lane * 8;
  unsigned int* myflag = flags + ((rg * 4 + q) << 4);

  float y[2][4], acc[2][4], k[2][4];
#pragma unroll
  for (int n = 0; n < 2; n++)
#pragma unroll
    for (int r = 0; r < 4; r++) {
      const int row = rowbase + quad * 4 + r;
      const int col = cw2 + n * 16 + m;
      y[n][r] = ldf(y0, row * D_ + col, f32i);
      if (q == 0) out[(size_t)row * D_ + col] = y[n][r];   // t=0 plane
      k[n][r] = 0.0f;
      acc[n][r] = 0.0f;
    }

#pragma unroll 1
  for (int step = 0; step < T_ - 1; step++) {
    const float dt = ldf(ts, step + 1, f32i) - ldf(ts, step, f32i);

#pragma unroll 1
    for (int e = 0; e < 4; e++) {
      const float c = (e == 0) ? 0.0f : ((e == 3) ? dt : 0.5f * dt);
      const float wgt = ((e == 1) || (e == 2)) ? 2.0f : 1.0f;
      const int sidx = step * 4 + e;
      const int par  = sidx & 1;

      // ---- stage yin = y + c*k into LDS (fp16), all 512 cols ----
#pragma unroll
      for (int n = 0; n < 2; n++)
#pragma unroll
        for (int r = 0; r < 4; r++)
          yS[quad * 4 + r][cw2 + n * 16 + m] = f2h(y[n][r] + c * k[n][r]);
      __syncthreads();

      // ---- GEMM1: h quarter = yin @ W1[:, q-slice], 1 tile/wave, K=512 ----
      f32x4 hacc = (f32x4){0.f, 0.f, 0.f, 0.f};
      f16x8 a0 = ld8(&yS[m][quad * 8]);
      f16x8 b0 = ld8(q1);
#pragma unroll 4
      for (int t = 0; t < 16; t++) {
        const int tn = (t + 1) & 15;   // dummy wrap prefetch
        f16x8 a1 = ld8(&yS[m][tn * 32 + quad * 8]);
        f16x8 bn = ld8(q1 + tn * 512);
        hacc = mfma16f(a0, b0, hacc);
        a0 = a1; b0 = bn;
      }

      // ---- bias + tanh -> hS (fp16, local 256 cols) ----
#pragma unroll
      for (int r = 0; r < 4; r++)
        hS[quad * 4 + r][wave * 16 + m] = f2h(tanh_fast(hacc[r] + b1v));
      __syncthreads();

      // ---- GEMM2: partial k = h_q @ W2[q-slice, :], 2 tiles/wave, K=256 ----
      f32x4 kacc[2];
#pragma unroll
      for (int n = 0; n < 2; n++) kacc[n] = (f32x4){0.f, 0.f, 0.f, 0.f};
      f16x8 c0 = ld8(&hS[m][quad * 8]);
      f16x8 d0 = ld8(q2);
      f16x8 d1 = ld8(q2 + 512);
#pragma unroll 4
      for (int t = 0; t < 8; t++) {
        const int tn = (t + 1) & 7;    // dummy wrap prefetch
        f16x8 a1 = ld8(&hS[m][tn * 32 + quad * 8]);
        f16x8 e0 = ld8(q2 + tn * 1024);
        f16x8 e1 = ld8(q2 + tn * 1024 + 512);
        kacc[0] = mfma16f(c0, d0, kacc[0]);
        kacc[1] = mfma16f(c0, d1, kacc[1]);
        c0 = a1; d0 = e0; d1 = e1;
      }

      // ---- publish partial [16][512] fp32 (cached stores) ----
      {
        float* pb = part + ((size_t)((par * 64 + rg) * 4 + q) << 13);
#pragma unroll
        for (int n = 0; n < 2; n++)
#pragma unroll
          for (int r = 0; r < 4; r++)
            pb[(quad * 4 + r) * 512 + cw2 + n * 16 + m] = kacc[n][r];
      }
      __syncthreads();
      if (tid == 0) {
        // RELEASE: s_waitcnt + buffer_wbl2 (write-back, NO invalidate) + L3 atomic.
        // Weights stay L2-resident -- this is the R8->R9 fix.
        __hip_atomic_fetch_add(myflag, 1u, __ATOMIC_RELEASE,
                               __HIP_MEMORY_SCOPE_AGENT);
      }
      // ---- gather partner flags (threads 0..3, skip own; relaxed = no inv) ----
      if (tid < 4 && tid != q) {
        unsigned int* pf = flags + ((rg * 4 + tid) << 4);
        const unsigned int tgt = (unsigned int)(sidx + 1);
        int spins = 0;
        while (__hip_atomic_load(pf, __ATOMIC_RELAXED,
                                 __HIP_MEMORY_SCOPE_AGENT) < tgt) {
          __builtin_amdgcn_s_sleep(1);
          if (++spins > (1 << 19)) break;   // anti-wedge valve (never hit normally)
        }
      }
      __syncthreads();

      // ---- assemble k = b2 + sum_q partial (canonical order; sc1 loads bypass
      //      L1/L2 -> fresh from Infinity Cache; own quarter's round-trip is
      //      bit-identical to kacc, so replicas stay identical) ----
      {
        const float* pr = part + ((size_t)((par * 64 + rg) * 4) << 13);
        float tp[4][2][4];
#pragma unroll
        for (int qq = 0; qq < 4; qq++)
#pragma unroll
          for (int n = 0; n < 2; n++)
#pragma unroll
            for (int r = 0; r < 4; r++)
              tp[qq][n][r] = __hip_atomic_load(
                  pr + ((size_t)qq << 13) + (size_t)(quad * 4 + r) * 512 +
                      cw2 + n * 16 + m,
                  __ATOMIC_RELAXED, __HIP_MEMORY_SCOPE_AGENT);
#pragma unroll
        for (int n = 0; n < 2; n++)
#pragma unroll
          for (int r = 0; r < 4; r++) {
            float s = b2v[n];
#pragma unroll
            for (int qq = 0; qq < 4; qq++) s += tp[qq][n][r];
            k[n][r] = s;
            if (e == 0) acc[n][r] = k[n][r];
            else        acc[n][r] += wgt * k[n][r];
          }
      }
    }

    // ---- y update + fp32 output store (q==0 only) ----
    float* op = out + (size_t)(step + 1) * B_ * D_;
    const float s = dt * (1.0f / 6.0f);
#pragma unroll
    for (int n = 0; n < 2; n++)
#pragma unroll
      for (int r = 0; r < 4; r++) {
        y[n][r] += s * acc[n][r];
        if (q == 0)
          op[(size_t)(rowbase + quad * 4 + r) * D_ + cw2 + n * 16 + m] = y[n][r];
      }
  }
}

extern "C" void kernel_launch(void* const* d_in, const int* in_sizes, int n_in,
                              void* d_out, int out_size, void* d_ws, size_t ws_size,
                              hipStream_t stream) {
  // ---- role mapping from in_sizes (proven R5): elements-or-bytes, dict-or-alpha ----
  int iTs = -1, sc = 1;
  for (int i = 0; i < n_in; i++)
    if (in_sizes[i] == 64 || in_sizes[i] == 128 || in_sizes[i] == 256) {
      iTs = i; sc = in_sizes[i] / 64; break;
    }
  if (iTs < 0) { iTs = 1; sc = 1; }
  int iB1 = -1, iB2 = -1, bigs[3]; int nb = 0;
  for (int i = 0; i < n_in; i++) {
    if (i == iTs) continue;
    if (in_sizes[i] == 1024 * sc) iB1 = i;
    else if (in_sizes[i] == 512 * sc) iB2 = i;
    else if (nb < 3) bigs[nb++] = i;
  }
  if (iB1 < 0) iB1 = 3;
  if (iB2 < 0) iB2 = 5;
  if (nb < 3) { bigs[0] = 0; bigs[1] = 2; bigs[2] = 4; }
  const void *y0, *w1, *w2;
  if (iTs == 1) {            // dict order: first_point, ts, W1, b1, W2, b2
    y0 = d_in[bigs[0]]; w1 = d_in[bigs[1]]; w2 = d_in[bigs[2]];
  } else {                   // alphabetical: W1, W2, b1, b2, first_point, ts
    w1 = d_in[bigs[0]]; w2 = d_in[bigs[1]]; y0 = d_in[bigs[2]];
  }
  const void* ts = d_in[iTs];
  const void* b1 = d_in[iB1];
  const void* b2 = d_in[iB2];
  float* out = (float*)d_out;

  // ws layout: w1p 1MB | w2p 1MB | flags 16KB | partials 16MB
  char* wsb = (char*)d_ws;
  ushort_t* w1p = (ushort_t*)wsb;
  ushort_t* w2p = (ushort_t*)(wsb + (1 << 20));
  unsigned int* flags = (unsigned int*)(wsb + (2 << 20));
  float* part = (float*)(wsb + (2 << 20) + 16384);

  hipMemsetAsync(flags, 0, 16384, stream);   // monotone counters start at 0

  pack_w1<<<dim3(256), dim3(256), 0, stream>>>(w1, w1p, ts);
  pack_w2<<<dim3(256), dim3(256), 0, stream>>>(w2, w2p, ts);

  rk4_kernel<<<dim3(256), dim3(1024), 0, stream>>>(y0, ts, w1p, b1, w2p, b2,
                                                   part, flags, out);
}